// Round 26
// baseline (112.560 us; speedup 1.0000x reference)
//
#include <hip/hip_runtime.h>

// SAGAN self-attention, B=4 C=256 H=W=64 (N=4096), CK=32.
//   f = fw@x+fb, g = gw@x+gb, hv = hw@x+hb         (channel 1x1 convs)
//   s[j,m] = sum_k f[k,j] g[k,m];  L[j] = sum_m exp(s[j,m])
//   w[c,j] = hv[c,j]/L[j];  sa[c,m] = sum_j w[c,j] exp(s[j,m]);  out = gamma*sa+x
//
// R24: pass2 pipes sum to ~86% (MFMA 30 + VALU 31 + TRANS 25) — near the
// aggregate issue limit. Last addressable waste: ~40 VGPR rotation moves/iter
// (~7%). This round: 2x-unrolled loop with alternating A/B register banks
// (zero moves, same explicit 1-ahead prefetch). proj/pass1/wdiv unchanged.
//
// Fragment layouts (verified R17/R18):
//  hvF: element (c,j) at b*2^20 +
//    (32*(j>>6) + 8*(c>>6) + 4*((j>>5)&1) + ((c>>4)&3))*512
//    + (((j>>2)&3)*16 + (c&15))*8 + ((j>>4)&1)*4 + (j&3)
//  fF: f[k][j] (k<32) at frag = ((b*64 + (j>>6))*2 + ((j>>5)&1))*2 + ((j>>4)&1);
//    elem = frag*512 + ((k>>3)*16 + (j&15))*8 + (k&7)
//  gT[b][m][32]: g channel-contiguous per m.
//
// ws layout (bytes) — total 10,747,904:
//   gT   [4][4096][32] bf16  @ 0         (1,048,576)
//   fF   fragment-order bf16 @ 1048576   (1,048,576)
//   hvF  fragment-order bf16 @ 2097152   (8,388,608)
//   Lp   [4][4][4096]  f32   @ 10485760  (262,144)
//
// XCD map (grid%8==0): b=(bid&7)>>1 pins each batch's data to one XCD pair L2.

typedef __bf16 bf16x4 __attribute__((ext_vector_type(4)));
typedef __bf16 bf16x8 __attribute__((ext_vector_type(8)));
typedef float  f32x4  __attribute__((ext_vector_type(4)));

static __device__ __forceinline__ bf16x8 cvt8(f32x4 lo, f32x4 hi) {
  bf16x8 r;
  r[0]=(__bf16)lo[0]; r[1]=(__bf16)lo[1]; r[2]=(__bf16)lo[2]; r[3]=(__bf16)lo[3];
  r[4]=(__bf16)hi[0]; r[5]=(__bf16)hi[1]; r[6]=(__bf16)hi[2]; r[7]=(__bf16)hi[3];
  return r;
}

// ---------------- proj: x read ONCE; block = 32 n-cols x all 320 m-rows (R21) ----
__global__ __launch_bounds__(256, 2) void k_proj(
    const float* __restrict__ fw, const float* __restrict__ gw,
    const float* __restrict__ hw, const float* __restrict__ x,
    const float* __restrict__ fb, const float* __restrict__ gb,
    const float* __restrict__ hb,
    __bf16* __restrict__ gT, __bf16* __restrict__ fF, __bf16* __restrict__ hvF) {
  __shared__ __bf16 Bs[2][32][40];   // 5,120 B
  const int bid = blockIdx.x;
  const int b = (bid & 7) >> 1;
  const int n0 = (((bid >> 3) << 1) | (bid & 1)) * 32;
  const int t = threadIdx.x, mq = t >> 6, lane = t & 63, r16 = lane & 15, h = lane >> 4;
  const float* xb = x + (size_t)b * (256 * 4096);
  const float* Wp[5];
  #pragma unroll
  for (int mt = 0; mt < 5; ++mt) {
    const int wrow = mq * 80 + mt * 16 + r16;
    Wp[mt] = wrow < 32 ? (fw + wrow * 256)
           : wrow < 64 ? (gw + (wrow - 32) * 256)
                       : (hw + (wrow - 64) * 256);
  }
  const int kk = t >> 3, nc = (t & 7) * 4;          // 32k x 32n staging
  f32x4 acc[5][2] = {};
  {
    f32x4 xv = *(const f32x4*)&xb[(size_t)kk * 4096 + n0 + nc];
    Bs[0][nc + 0][kk] = (__bf16)xv[0]; Bs[0][nc + 1][kk] = (__bf16)xv[1];
    Bs[0][nc + 2][kk] = (__bf16)xv[2]; Bs[0][nc + 3][kk] = (__bf16)xv[3];
  }
  __syncthreads();
  for (int ks = 0; ks < 8; ++ks) {
    const int cur = ks & 1;
    f32x4 xn;
    if (ks < 7) xn = *(const f32x4*)&xb[(size_t)((ks + 1) * 32 + kk) * 4096 + n0 + nc];
    bf16x8 bf0 = *(const bf16x8*)&Bs[cur][r16][h * 8];
    bf16x8 bf1 = *(const bf16x8*)&Bs[cur][16 + r16][h * 8];
    #pragma unroll
    for (int mt = 0; mt < 5; ++mt) {
      f32x4 wlo = *(const f32x4*)(Wp[mt] + ks * 32 + h * 8);
      f32x4 whi = *(const f32x4*)(Wp[mt] + ks * 32 + h * 8 + 4);
      bf16x8 af = cvt8(wlo, whi);
      acc[mt][0] = __builtin_amdgcn_mfma_f32_16x16x32_bf16(af, bf0, acc[mt][0], 0, 0, 0);
      acc[mt][1] = __builtin_amdgcn_mfma_f32_16x16x32_bf16(af, bf1, acc[mt][1], 0, 0, 0);
    }
    if (ks < 7) {
      const int nxt = cur ^ 1;
      Bs[nxt][nc + 0][kk] = (__bf16)xn[0]; Bs[nxt][nc + 1][kk] = (__bf16)xn[1];
      Bs[nxt][nc + 2][kk] = (__bf16)xn[2]; Bs[nxt][nc + 3][kk] = (__bf16)xn[3];
    }
    __syncthreads();
  }
  #pragma unroll
  for (int mt = 0; mt < 5; ++mt) {
    #pragma unroll
    for (int nt = 0; nt < 2; ++nt) {
      const int nn = n0 + nt * 16 + r16;
      const int fragn = (((b * 64 + (nn >> 6)) * 2 + ((nn >> 5) & 1)) * 2 + ((nn >> 4) & 1));
      const int jt2 = nn >> 6, jh2 = (nn >> 5) & 1;
      const int h2 = (nn >> 2) & 3, s2 = (nn >> 4) & 1, b2 = nn & 3;
      #pragma unroll
      for (int r = 0; r < 4; ++r) {
        const int row = mq * 80 + mt * 16 + h * 4 + r;  // C/D: row=(lane>>4)*4+reg
        const float bias = row < 32 ? fb[row] : (row < 64 ? gb[row - 32] : hb[row - 64]);
        float val = acc[mt][nt][r] + bias;
        if (row < 32) {
          val *= 1.44269504089f;                        // f * log2(e)
          const size_t off = (size_t)fragn * 512
            + (size_t)(((row >> 3) * 16 + (nn & 15)) * 8) + (row & 7);
          fF[off] = (__bf16)val;
        } else if (row < 64) {
          gT[((size_t)b * 4096 + nn) * 32 + (row - 32)] = (__bf16)val;
        } else {
          const int c = row - 64;
          const size_t off = (size_t)b * 1048576
            + (size_t)(32 * jt2 + 8 * (c >> 6) + 4 * jh2 + ((c >> 4) & 3)) * 512
            + (h2 * 16 + (c & 15)) * 8 + s2 * 4 + b2;
          hvF[off] = (__bf16)val;
        }
      }
    }
  }
}

// ---------------- pass1: L[i] = sum_m exp2(f'_i . g_m)  (partial, m-quarter) ----
__global__ __launch_bounds__(256) void k_pass1(const __bf16* __restrict__ gT,
                                               const __bf16* __restrict__ fF,
                                               float* __restrict__ Lp) {
  const int bid = blockIdx.x;
  const int b = (bid & 7) >> 1;
  const int sub = ((bid >> 3) << 1) | (bid & 1);
  const int ms = sub >> 6, ib = sub & 63;
  const int w = threadIdx.x >> 6, lane = threadIdx.x & 63, r16 = lane & 15, h = lane >> 4;
  const __bf16* gb_ = gT + (size_t)b * 4096 * 32;
  const int fragn = ((b * 64 + ib) * 2 + (w >> 1)) * 2 + (w & 1);
  const bf16x8 afrag = *(const bf16x8*)(fF + (size_t)fragn * 512 + lane * 8);
  const f32x4 zero = {};
  float ls0 = 0.f, ls1 = 0.f, ls2 = 0.f, ls3 = 0.f;
  const int mb0 = ms * 1024;
  bf16x8 g0 = *(const bf16x8*)(gb_ + (size_t)(mb0 + r16) * 32 + h * 8);
  bf16x8 g1 = *(const bf16x8*)(gb_ + (size_t)(mb0 + 16 + r16) * 32 + h * 8);
  for (int mt = 0; mt < 64; mt += 2) {
    bf16x8 ng0, ng1;
    if (mt < 62) {
      const int mbn = mb0 + (mt + 2) * 16;
      ng0 = *(const bf16x8*)(gb_ + (size_t)(mbn + r16) * 32 + h * 8);
      ng1 = *(const bf16x8*)(gb_ + (size_t)(mbn + 16 + r16) * 32 + h * 8);
    }
    f32x4 d0 = __builtin_amdgcn_mfma_f32_16x16x32_bf16(afrag, g0, zero, 0, 0, 0);
    f32x4 d1 = __builtin_amdgcn_mfma_f32_16x16x32_bf16(afrag, g1, zero, 0, 0, 0);
    ls0 += __builtin_amdgcn_exp2f(d0[0]) + __builtin_amdgcn_exp2f(d1[0]);
    ls1 += __builtin_amdgcn_exp2f(d0[1]) + __builtin_amdgcn_exp2f(d1[1]);
    ls2 += __builtin_amdgcn_exp2f(d0[2]) + __builtin_amdgcn_exp2f(d1[2]);
    ls3 += __builtin_amdgcn_exp2f(d0[3]) + __builtin_amdgcn_exp2f(d1[3]);
    if (mt < 62) { g0 = ng0; g1 = ng1; }
  }
  #pragma unroll
  for (int off = 1; off < 16; off <<= 1) {
    ls0 += __shfl_xor(ls0, off); ls1 += __shfl_xor(ls1, off);
    ls2 += __shfl_xor(ls2, off); ls3 += __shfl_xor(ls3, off);
  }
  if (r16 == 0) {
    f32x4 o = {ls0, ls1, ls2, ls3};
    *(f32x4*)&Lp[(size_t)(b * 4 + ms) * 4096 + ib * 64 + w * 16 + h * 4] = o;
  }
}

// ---------------- wdiv: hvF /= L, elementwise in place (fragment layout) -----
__global__ __launch_bounds__(256) void k_wdiv(__bf16* __restrict__ hvF,
                                              const float* __restrict__ Lp) {
  const int bid = blockIdx.x;                       // 512
  const int b = (bid & 7) >> 1;
  const int chunk = ((bid >> 3) << 1) | (bid & 1);  // 0..127
  const int t = threadIdx.x;
  const int o = chunk * 8192 + t * 32;              // element offset in batch
  const int frag = o >> 9;                          // 32jt+8cq+4jh+ct
  const int jh = (frag >> 2) & 1;
  const int jt = frag >> 5;
  const int l0 = (o >> 3) & 63;
  const int jb = jt * 64 + jh * 32 + ((l0 >> 4) << 2);
  const float* lp = Lp + (size_t)b * 16384 + jb;
  f32x4 La = *(const f32x4*)lp;
  La += *(const f32x4*)(lp + 4096);
  La += *(const f32x4*)(lp + 8192);
  La += *(const f32x4*)(lp + 12288);
  f32x4 Lb = *(const f32x4*)(lp + 16);
  Lb += *(const f32x4*)(lp + 16 + 4096);
  Lb += *(const f32x4*)(lp + 16 + 8192);
  Lb += *(const f32x4*)(lp + 16 + 12288);
  __bf16* p = hvF + (size_t)b * 1048576 + o;
  bf16x4 in[8];
  #pragma unroll
  for (int k = 0; k < 8; ++k) in[k] = *(const bf16x4*)(p + k * 4);
  #pragma unroll
  for (int k = 0; k < 8; ++k) {
    const f32x4 L = (k & 1) ? Lb : La;
    bf16x4 ov;
    #pragma unroll
    for (int bb = 0; bb < 4; ++bb)
      ov[bb] = (__bf16)((float)in[k][bb] / L[bb]);
    *(bf16x4*)(p + k * 4) = ov;
  }
}

// ---------------- pass2: 128c x 128m, 2x-unrolled A/B register banks ---------
// 256 blocks x 512 threads (1 block/CU, 8 waves = msub0..3 x jh). Iteration p:
// prefetch B(2p+1) -> compute A(2p) -> prefetch A(2p+2) -> compute B(2p+1).
// Zero register-rotation moves; explicit in-flight prefetch preserved.
#define P2_LOAD(BANKa0,BANKa1,BANKa2,BANKa3,BANKa4,BANKa5,BANKa6,BANKa7,BANKf0,BANKf1,TILE) \
  { const __bf16* wn_ = wbase + (size_t)(TILE) * 16384;                      \
    BANKa0 = *(const bf16x8*)(wn_ + wo[0]);                                  \
    BANKa1 = *(const bf16x8*)(wn_ + wo[1]);                                  \
    BANKa2 = *(const bf16x8*)(wn_ + wo[2]);                                  \
    BANKa3 = *(const bf16x8*)(wn_ + wo[3]);                                  \
    BANKa4 = *(const bf16x8*)(wn_ + wo[4]);                                  \
    BANKa5 = *(const bf16x8*)(wn_ + wo[5]);                                  \
    BANKa6 = *(const bf16x8*)(wn_ + wo[6]);                                  \
    BANKa7 = *(const bf16x8*)(wn_ + wo[7]);                                  \
    const __bf16* fn_ = fbase + (size_t)(TILE) * 2048;                       \
    BANKf0 = *(const bf16x8*)(fn_);                                          \
    BANKf1 = *(const bf16x8*)(fn_ + 512); }

#define P2_COMPUTE(BANKa0,BANKa1,BANKa2,BANKa3,BANKa4,BANKa5,BANKa6,BANKa7,BANKf0,BANKf1) \
  { f32x4 d0_ = __builtin_amdgcn_mfma_f32_16x16x32_bf16(BANKf0, gf0, zero, 0, 0, 0); \
    f32x4 d1_ = __builtin_amdgcn_mfma_f32_16x16x32_bf16(BANKf1, gf0, zero, 0, 0, 0); \
    f32x4 d2_ = __builtin_amdgcn_mfma_f32_16x16x32_bf16(BANKf0, gf1, zero, 0, 0, 0); \
    f32x4 d3_ = __builtin_amdgcn_mfma_f32_16x16x32_bf16(BANKf1, gf1, zero, 0, 0, 0); \
    bf16x8 ef0_, ef1_;                                                       \
    _Pragma("unroll")                                                        \
    for (int r_ = 0; r_ < 4; ++r_) {                                         \
      ef0_[r_]     = (__bf16)__builtin_amdgcn_exp2f(d0_[r_]);                \
      ef0_[4 + r_] = (__bf16)__builtin_amdgcn_exp2f(d1_[r_]);                \
      ef1_[r_]     = (__bf16)__builtin_amdgcn_exp2f(d2_[r_]);                \
      ef1_[4 + r_] = (__bf16)__builtin_amdgcn_exp2f(d3_[r_]);                \
    }                                                                        \
    acc[0]  = __builtin_amdgcn_mfma_f32_16x16x32_bf16(BANKa0, ef0_, acc[0],  0, 0, 0); \
    acc2[0] = __builtin_amdgcn_mfma_f32_16x16x32_bf16(BANKa0, ef1_, acc2[0], 0, 0, 0); \
    acc[1]  = __builtin_amdgcn_mfma_f32_16x16x32_bf16(BANKa1, ef0_, acc[1],  0, 0, 0); \
    acc2[1] = __builtin_amdgcn_mfma_f32_16x16x32_bf16(BANKa1, ef1_, acc2[1], 0, 0, 0); \
    acc[2]  = __builtin_amdgcn_mfma_f32_16x16x32_bf16(BANKa2, ef0_, acc[2],  0, 0, 0); \
    acc2[2] = __builtin_amdgcn_mfma_f32_16x16x32_bf16(BANKa2, ef1_, acc2[2], 0, 0, 0); \
    acc[3]  = __builtin_amdgcn_mfma_f32_16x16x32_bf16(BANKa3, ef0_, acc[3],  0, 0, 0); \
    acc2[3] = __builtin_amdgcn_mfma_f32_16x16x32_bf16(BANKa3, ef1_, acc2[3], 0, 0, 0); \
    acc[4]  = __builtin_amdgcn_mfma_f32_16x16x32_bf16(BANKa4, ef0_, acc[4],  0, 0, 0); \
    acc2[4] = __builtin_amdgcn_mfma_f32_16x16x32_bf16(BANKa4, ef1_, acc2[4], 0, 0, 0); \
    acc[5]  = __builtin_amdgcn_mfma_f32_16x16x32_bf16(BANKa5, ef0_, acc[5],  0, 0, 0); \
    acc2[5] = __builtin_amdgcn_mfma_f32_16x16x32_bf16(BANKa5, ef1_, acc2[5], 0, 0, 0); \
    acc[6]  = __builtin_amdgcn_mfma_f32_16x16x32_bf16(BANKa6, ef0_, acc[6],  0, 0, 0); \
    acc2[6] = __builtin_amdgcn_mfma_f32_16x16x32_bf16(BANKa6, ef1_, acc2[6], 0, 0, 0); \
    acc[7]  = __builtin_amdgcn_mfma_f32_16x16x32_bf16(BANKa7, ef0_, acc[7],  0, 0, 0); \
    acc2[7] = __builtin_amdgcn_mfma_f32_16x16x32_bf16(BANKa7, ef1_, acc2[7], 0, 0, 0); }

__global__ __launch_bounds__(512, 2) void k_pass2(const __bf16* __restrict__ gT,
    const __bf16* __restrict__ fF, const __bf16* __restrict__ wF,
    const float* __restrict__ x, const float* __restrict__ gamma,
    float* __restrict__ out) {
  __shared__ float red[16384];                      // epilogue only (64 KB)
  const int bid = blockIdx.x;
  const int b = (bid & 7) >> 1;                     // XCD pair per batch
  const int sub = ((bid >> 3) << 1) | (bid & 1);    // 0..63
  const int ch = sub >> 5;                          // c-half: rows ch*128..+127
  const int mblk = sub & 31;                        // 128 m each
  const int t = threadIdx.x, w = t >> 6, lane = t & 63, r16 = lane & 15, h = lane >> 4;
  const int jh = w & 1, msub = w >> 1;              // msub 0..3
  const int mbase = mblk * 128 + msub * 32;
  const __bf16* gb_ = gT + (size_t)b * 4096 * 32;
  const bf16x8 gf0 = *(const bf16x8*)(gb_ + (size_t)(mbase + r16) * 32 + h * 8);
  const bf16x8 gf1 = *(const bf16x8*)(gb_ + (size_t)(mbase + 16 + r16) * 32 + h * 8);
  const __bf16* wbase = wF + (size_t)b * 1048576 + lane * 8;
  size_t wo[8];
  #pragma unroll
  for (int ctt = 0; ctt < 8; ++ctt)
    wo[ctt] = (size_t)(8 * (2 * ch + (ctt >> 2)) + 4 * jh + (ctt & 3)) * 512;
  const __bf16* fbase = fF + ((size_t)(b * 64) * 2 + jh) * 2 * 512 + lane * 8;
  const f32x4 zero = {};

  f32x4 acc[8] = {};
  f32x4 acc2[8] = {};

  bf16x8 Aa0, Aa1, Aa2, Aa3, Aa4, Aa5, Aa6, Aa7, Af0, Af1;
  bf16x8 Ba0, Ba1, Ba2, Ba3, Ba4, Ba5, Ba6, Ba7, Bf0, Bf1;

  P2_LOAD(Aa0, Aa1, Aa2, Aa3, Aa4, Aa5, Aa6, Aa7, Af0, Af1, 0)

  for (int p = 0; p < 32; ++p) {
    P2_LOAD(Ba0, Ba1, Ba2, Ba3, Ba4, Ba5, Ba6, Ba7, Bf0, Bf1, 2 * p + 1)
    P2_COMPUTE(Aa0, Aa1, Aa2, Aa3, Aa4, Aa5, Aa6, Aa7, Af0, Af1)
    if (p < 31)
      P2_LOAD(Aa0, Aa1, Aa2, Aa3, Aa4, Aa5, Aa6, Aa7, Af0, Af1, 2 * p + 2)
    P2_COMPUTE(Ba0, Ba1, Ba2, Ba3, Ba4, Ba5, Ba6, Ba7, Bf0, Bf1)
  }

  // epilogue: jh=1 waves dump partials, jh=0 adds + writes out.
  __syncthreads();
  const int region = msub * 4096;                   // 4 regions x 16KB (floats)
  if (jh == 1) {
    #pragma unroll
    for (int ct = 0; ct < 8; ++ct) {
      *(f32x4*)&red[region + ((ct * 2 + 0) * 64 + lane) * 4] = acc[ct];
      *(f32x4*)&red[region + ((ct * 2 + 1) * 64 + lane) * 4] = acc2[ct];
    }
  }
  __syncthreads();
  if (jh == 0) {
    const float gm = gamma[0];
    const float* xb = x + (size_t)b * (256 * 4096);
    float* ob = out + (size_t)b * (256 * 4096);
    #pragma unroll
    for (int ct = 0; ct < 8; ++ct) {
      #pragma unroll
      for (int mt = 0; mt < 2; ++mt) {
        f32x4 o = *(const f32x4*)&red[region + ((ct * 2 + mt) * 64 + lane) * 4];
        o += (mt == 0) ? acc[ct] : acc2[ct];
        #pragma unroll
        for (int r = 0; r < 4; ++r) {
          const int c = ch * 128 + ct * 16 + h * 4 + r;
          const size_t idx = (size_t)c * 4096 + (mbase + mt * 16 + r16);
          ob[idx] = gm * o[r] + xb[idx];
        }
      }
    }
  }
}

extern "C" void kernel_launch(void* const* d_in, const int* in_sizes, int n_in,
                              void* d_out, int out_size, void* d_ws, size_t ws_size,
                              hipStream_t stream) {
  const float* x     = (const float*)d_in[0];
  const float* fw    = (const float*)d_in[1];
  const float* fb    = (const float*)d_in[2];
  const float* gw    = (const float*)d_in[3];
  const float* gb    = (const float*)d_in[4];
  const float* hw    = (const float*)d_in[5];
  const float* hb    = (const float*)d_in[6];
  const float* gamma = (const float*)d_in[7];
  float* out = (float*)d_out;

  char* wsb = (char*)d_ws;
  __bf16* gT  = (__bf16*)(wsb);
  __bf16* fF  = (__bf16*)(wsb + 1048576);
  __bf16* hvF = (__bf16*)(wsb + 2097152);
  float*  Lp  = (float*) (wsb + 10485760);

  k_proj<<<dim3(512), dim3(256), 0, stream>>>(fw, gw, hw, x, fb, gb, hb, gT, fF, hvF);
  k_pass1<<<dim3(1024), dim3(256), 0, stream>>>(gT, fF, Lp);
  k_wdiv<<<dim3(512), dim3(256), 0, stream>>>(hvF, Lp);
  k_pass2<<<dim3(256), dim3(512), 0, stream>>>(gT, fF, hvF, x, gamma, out);
}

// Round 27
// 101.634 us; speedup vs baseline: 1.1075x; 1.1075x over previous
//
#include <hip/hip_runtime.h>

// SAGAN self-attention, B=4 C=256 H=W=64 (N=4096), CK=32.
//   f = fw@x+fb, g = gw@x+gb, hv = hw@x+hb         (channel 1x1 convs)
//   s[j,m] = sum_k f[k,j] g[k,m];  L[j] = sum_m exp(s[j,m])
//   w[c,j] = hv[c,j]/L[j];  sa[c,m] = sum_j w[c,j] exp(s[j,m]);  out = gamma*sa+x
//
// R25 lesson: hand-unrolled A/B banks defeated the compiler's schedule
// (57->69.5us, VGPR 72->88). FINAL: restore the measured-best R24 config —
// rolled pass2 loop + explicit 1-ahead prefetch (57us), proj 32n (R21),
// pass1 w/ g-prefetch, wdiv fragment-layout. Total best measured: 101.7us.
//
// Fragment layouts (verified R17/R18):
//  hvF: element (c,j) at b*2^20 +
//    (32*(j>>6) + 8*(c>>6) + 4*((j>>5)&1) + ((c>>4)&3))*512
//    + (((j>>2)&3)*16 + (c&15))*8 + ((j>>4)&1)*4 + (j&3)
//  fF: f[k][j] (k<32) at frag = ((b*64 + (j>>6))*2 + ((j>>5)&1))*2 + ((j>>4)&1);
//    elem = frag*512 + ((k>>3)*16 + (j&15))*8 + (k&7)
//  gT[b][m][32]: g channel-contiguous per m.
//
// ws layout (bytes) — total 10,747,904:
//   gT   [4][4096][32] bf16  @ 0         (1,048,576)
//   fF   fragment-order bf16 @ 1048576   (1,048,576)
//   hvF  fragment-order bf16 @ 2097152   (8,388,608)
//   Lp   [4][4][4096]  f32   @ 10485760  (262,144)
//
// XCD map (grid%8==0): b=(bid&7)>>1 pins each batch's data to one XCD pair L2.

typedef __bf16 bf16x4 __attribute__((ext_vector_type(4)));
typedef __bf16 bf16x8 __attribute__((ext_vector_type(8)));
typedef float  f32x4  __attribute__((ext_vector_type(4)));

static __device__ __forceinline__ bf16x8 cvt8(f32x4 lo, f32x4 hi) {
  bf16x8 r;
  r[0]=(__bf16)lo[0]; r[1]=(__bf16)lo[1]; r[2]=(__bf16)lo[2]; r[3]=(__bf16)lo[3];
  r[4]=(__bf16)hi[0]; r[5]=(__bf16)hi[1]; r[6]=(__bf16)hi[2]; r[7]=(__bf16)hi[3];
  return r;
}

// ---------------- proj: x read ONCE; block = 32 n-cols x all 320 m-rows (R21) ----
__global__ __launch_bounds__(256, 2) void k_proj(
    const float* __restrict__ fw, const float* __restrict__ gw,
    const float* __restrict__ hw, const float* __restrict__ x,
    const float* __restrict__ fb, const float* __restrict__ gb,
    const float* __restrict__ hb,
    __bf16* __restrict__ gT, __bf16* __restrict__ fF, __bf16* __restrict__ hvF) {
  __shared__ __bf16 Bs[2][32][40];   // 5,120 B
  const int bid = blockIdx.x;
  const int b = (bid & 7) >> 1;
  const int n0 = (((bid >> 3) << 1) | (bid & 1)) * 32;
  const int t = threadIdx.x, mq = t >> 6, lane = t & 63, r16 = lane & 15, h = lane >> 4;
  const float* xb = x + (size_t)b * (256 * 4096);
  const float* Wp[5];
  #pragma unroll
  for (int mt = 0; mt < 5; ++mt) {
    const int wrow = mq * 80 + mt * 16 + r16;
    Wp[mt] = wrow < 32 ? (fw + wrow * 256)
           : wrow < 64 ? (gw + (wrow - 32) * 256)
                       : (hw + (wrow - 64) * 256);
  }
  const int kk = t >> 3, nc = (t & 7) * 4;          // 32k x 32n staging
  f32x4 acc[5][2] = {};
  {
    f32x4 xv = *(const f32x4*)&xb[(size_t)kk * 4096 + n0 + nc];
    Bs[0][nc + 0][kk] = (__bf16)xv[0]; Bs[0][nc + 1][kk] = (__bf16)xv[1];
    Bs[0][nc + 2][kk] = (__bf16)xv[2]; Bs[0][nc + 3][kk] = (__bf16)xv[3];
  }
  __syncthreads();
  for (int ks = 0; ks < 8; ++ks) {
    const int cur = ks & 1;
    f32x4 xn;
    if (ks < 7) xn = *(const f32x4*)&xb[(size_t)((ks + 1) * 32 + kk) * 4096 + n0 + nc];
    bf16x8 bf0 = *(const bf16x8*)&Bs[cur][r16][h * 8];
    bf16x8 bf1 = *(const bf16x8*)&Bs[cur][16 + r16][h * 8];
    #pragma unroll
    for (int mt = 0; mt < 5; ++mt) {
      f32x4 wlo = *(const f32x4*)(Wp[mt] + ks * 32 + h * 8);
      f32x4 whi = *(const f32x4*)(Wp[mt] + ks * 32 + h * 8 + 4);
      bf16x8 af = cvt8(wlo, whi);
      acc[mt][0] = __builtin_amdgcn_mfma_f32_16x16x32_bf16(af, bf0, acc[mt][0], 0, 0, 0);
      acc[mt][1] = __builtin_amdgcn_mfma_f32_16x16x32_bf16(af, bf1, acc[mt][1], 0, 0, 0);
    }
    if (ks < 7) {
      const int nxt = cur ^ 1;
      Bs[nxt][nc + 0][kk] = (__bf16)xn[0]; Bs[nxt][nc + 1][kk] = (__bf16)xn[1];
      Bs[nxt][nc + 2][kk] = (__bf16)xn[2]; Bs[nxt][nc + 3][kk] = (__bf16)xn[3];
    }
    __syncthreads();
  }
  #pragma unroll
  for (int mt = 0; mt < 5; ++mt) {
    #pragma unroll
    for (int nt = 0; nt < 2; ++nt) {
      const int nn = n0 + nt * 16 + r16;
      const int fragn = (((b * 64 + (nn >> 6)) * 2 + ((nn >> 5) & 1)) * 2 + ((nn >> 4) & 1));
      const int jt2 = nn >> 6, jh2 = (nn >> 5) & 1;
      const int h2 = (nn >> 2) & 3, s2 = (nn >> 4) & 1, b2 = nn & 3;
      #pragma unroll
      for (int r = 0; r < 4; ++r) {
        const int row = mq * 80 + mt * 16 + h * 4 + r;  // C/D: row=(lane>>4)*4+reg
        const float bias = row < 32 ? fb[row] : (row < 64 ? gb[row - 32] : hb[row - 64]);
        float val = acc[mt][nt][r] + bias;
        if (row < 32) {
          val *= 1.44269504089f;                        // f * log2(e)
          const size_t off = (size_t)fragn * 512
            + (size_t)(((row >> 3) * 16 + (nn & 15)) * 8) + (row & 7);
          fF[off] = (__bf16)val;
        } else if (row < 64) {
          gT[((size_t)b * 4096 + nn) * 32 + (row - 32)] = (__bf16)val;
        } else {
          const int c = row - 64;
          const size_t off = (size_t)b * 1048576
            + (size_t)(32 * jt2 + 8 * (c >> 6) + 4 * jh2 + ((c >> 4) & 3)) * 512
            + (h2 * 16 + (c & 15)) * 8 + s2 * 4 + b2;
          hvF[off] = (__bf16)val;
        }
      }
    }
  }
}

// ---------------- pass1: L[i] = sum_m exp2(f'_i . g_m)  (partial, m-quarter) ----
__global__ __launch_bounds__(256) void k_pass1(const __bf16* __restrict__ gT,
                                               const __bf16* __restrict__ fF,
                                               float* __restrict__ Lp) {
  const int bid = blockIdx.x;
  const int b = (bid & 7) >> 1;
  const int sub = ((bid >> 3) << 1) | (bid & 1);
  const int ms = sub >> 6, ib = sub & 63;
  const int w = threadIdx.x >> 6, lane = threadIdx.x & 63, r16 = lane & 15, h = lane >> 4;
  const __bf16* gb_ = gT + (size_t)b * 4096 * 32;
  const int fragn = ((b * 64 + ib) * 2 + (w >> 1)) * 2 + (w & 1);
  const bf16x8 afrag = *(const bf16x8*)(fF + (size_t)fragn * 512 + lane * 8);
  const f32x4 zero = {};
  float ls0 = 0.f, ls1 = 0.f, ls2 = 0.f, ls3 = 0.f;
  const int mb0 = ms * 1024;
  bf16x8 g0 = *(const bf16x8*)(gb_ + (size_t)(mb0 + r16) * 32 + h * 8);
  bf16x8 g1 = *(const bf16x8*)(gb_ + (size_t)(mb0 + 16 + r16) * 32 + h * 8);
  for (int mt = 0; mt < 64; mt += 2) {
    bf16x8 ng0, ng1;
    if (mt < 62) {
      const int mbn = mb0 + (mt + 2) * 16;
      ng0 = *(const bf16x8*)(gb_ + (size_t)(mbn + r16) * 32 + h * 8);
      ng1 = *(const bf16x8*)(gb_ + (size_t)(mbn + 16 + r16) * 32 + h * 8);
    }
    f32x4 d0 = __builtin_amdgcn_mfma_f32_16x16x32_bf16(afrag, g0, zero, 0, 0, 0);
    f32x4 d1 = __builtin_amdgcn_mfma_f32_16x16x32_bf16(afrag, g1, zero, 0, 0, 0);
    ls0 += __builtin_amdgcn_exp2f(d0[0]) + __builtin_amdgcn_exp2f(d1[0]);
    ls1 += __builtin_amdgcn_exp2f(d0[1]) + __builtin_amdgcn_exp2f(d1[1]);
    ls2 += __builtin_amdgcn_exp2f(d0[2]) + __builtin_amdgcn_exp2f(d1[2]);
    ls3 += __builtin_amdgcn_exp2f(d0[3]) + __builtin_amdgcn_exp2f(d1[3]);
    if (mt < 62) { g0 = ng0; g1 = ng1; }
  }
  #pragma unroll
  for (int off = 1; off < 16; off <<= 1) {
    ls0 += __shfl_xor(ls0, off); ls1 += __shfl_xor(ls1, off);
    ls2 += __shfl_xor(ls2, off); ls3 += __shfl_xor(ls3, off);
  }
  if (r16 == 0) {
    f32x4 o = {ls0, ls1, ls2, ls3};
    *(f32x4*)&Lp[(size_t)(b * 4 + ms) * 4096 + ib * 64 + w * 16 + h * 4] = o;
  }
}

// ---------------- wdiv: hvF /= L, elementwise in place (fragment layout) -----
__global__ __launch_bounds__(256) void k_wdiv(__bf16* __restrict__ hvF,
                                              const float* __restrict__ Lp) {
  const int bid = blockIdx.x;                       // 512
  const int b = (bid & 7) >> 1;
  const int chunk = ((bid >> 3) << 1) | (bid & 1);  // 0..127
  const int t = threadIdx.x;
  const int o = chunk * 8192 + t * 32;              // element offset in batch
  const int frag = o >> 9;                          // 32jt+8cq+4jh+ct
  const int jh = (frag >> 2) & 1;
  const int jt = frag >> 5;
  const int l0 = (o >> 3) & 63;
  const int jb = jt * 64 + jh * 32 + ((l0 >> 4) << 2);
  const float* lp = Lp + (size_t)b * 16384 + jb;
  f32x4 La = *(const f32x4*)lp;
  La += *(const f32x4*)(lp + 4096);
  La += *(const f32x4*)(lp + 8192);
  La += *(const f32x4*)(lp + 12288);
  f32x4 Lb = *(const f32x4*)(lp + 16);
  Lb += *(const f32x4*)(lp + 16 + 4096);
  Lb += *(const f32x4*)(lp + 16 + 8192);
  Lb += *(const f32x4*)(lp + 16 + 12288);
  __bf16* p = hvF + (size_t)b * 1048576 + o;
  bf16x4 in[8];
  #pragma unroll
  for (int k = 0; k < 8; ++k) in[k] = *(const bf16x4*)(p + k * 4);
  #pragma unroll
  for (int k = 0; k < 8; ++k) {
    const f32x4 L = (k & 1) ? Lb : La;
    bf16x4 ov;
    #pragma unroll
    for (int bb = 0; bb < 4; ++bb)
      ov[bb] = (__bf16)((float)in[k][bb] / L[bb]);
    *(bf16x4*)(p + k * 4) = ov;
  }
}

// ---------------- pass2: 128c x 128m blocks (L1-reuse), barrier-free (R24) ---
// 256 blocks x 512 threads (1 block/CU, 8 waves = msub0..3 x jh). Rolled loop
// with explicit 1-ahead prefetch (the compiler schedules this best: every
// hand-pipelined variant regressed). 57us measured.
__global__ __launch_bounds__(512, 2) void k_pass2(const __bf16* __restrict__ gT,
    const __bf16* __restrict__ fF, const __bf16* __restrict__ wF,
    const float* __restrict__ x, const float* __restrict__ gamma,
    float* __restrict__ out) {
  __shared__ float red[16384];                      // epilogue only (64 KB)
  const int bid = blockIdx.x;
  const int b = (bid & 7) >> 1;                     // XCD pair per batch
  const int sub = ((bid >> 3) << 1) | (bid & 1);    // 0..63
  const int ch = sub >> 5;                          // c-half: rows ch*128..+127
  const int mblk = sub & 31;                        // 128 m each
  const int t = threadIdx.x, w = t >> 6, lane = t & 63, r16 = lane & 15, h = lane >> 4;
  const int jh = w & 1, msub = w >> 1;              // msub 0..3
  const int mbase = mblk * 128 + msub * 32;
  const __bf16* gb_ = gT + (size_t)b * 4096 * 32;
  const bf16x8 gf0 = *(const bf16x8*)(gb_ + (size_t)(mbase + r16) * 32 + h * 8);
  const bf16x8 gf1 = *(const bf16x8*)(gb_ + (size_t)(mbase + 16 + r16) * 32 + h * 8);
  const __bf16* wbase = wF + (size_t)b * 1048576 + lane * 8;
  size_t wo[8];
  #pragma unroll
  for (int ctt = 0; ctt < 8; ++ctt)
    wo[ctt] = (size_t)(8 * (2 * ch + (ctt >> 2)) + 4 * jh + (ctt & 3)) * 512;
  const __bf16* fbase = fF + ((size_t)(b * 64) * 2 + jh) * 2 * 512 + lane * 8;
  const f32x4 zero = {};

  f32x4 acc[8] = {};
  f32x4 acc2[8] = {};

  bf16x8 a0 = *(const bf16x8*)(wbase + wo[0]);
  bf16x8 a1 = *(const bf16x8*)(wbase + wo[1]);
  bf16x8 a2 = *(const bf16x8*)(wbase + wo[2]);
  bf16x8 a3 = *(const bf16x8*)(wbase + wo[3]);
  bf16x8 a4 = *(const bf16x8*)(wbase + wo[4]);
  bf16x8 a5 = *(const bf16x8*)(wbase + wo[5]);
  bf16x8 a6 = *(const bf16x8*)(wbase + wo[6]);
  bf16x8 a7 = *(const bf16x8*)(wbase + wo[7]);
  bf16x8 fq0 = *(const bf16x8*)(fbase);
  bf16x8 fq1 = *(const bf16x8*)(fbase + 512);

  for (int it = 0; it < 64; ++it) {
    bf16x8 pa0, pa1, pa2, pa3, pa4, pa5, pa6, pa7, nf0, nf1;
    if (it < 63) {   // prefetch tile it+1 (coalesced 1KB each, L1/L2-hot)
      const __bf16* wn = wbase + (size_t)(it + 1) * 16384;
      pa0 = *(const bf16x8*)(wn + wo[0]);
      pa1 = *(const bf16x8*)(wn + wo[1]);
      pa2 = *(const bf16x8*)(wn + wo[2]);
      pa3 = *(const bf16x8*)(wn + wo[3]);
      pa4 = *(const bf16x8*)(wn + wo[4]);
      pa5 = *(const bf16x8*)(wn + wo[5]);
      pa6 = *(const bf16x8*)(wn + wo[6]);
      pa7 = *(const bf16x8*)(wn + wo[7]);
      const __bf16* fn = fbase + (size_t)(it + 1) * 2048;
      nf0 = *(const bf16x8*)(fn);
      nf1 = *(const bf16x8*)(fn + 512);
    }
    f32x4 d0 = __builtin_amdgcn_mfma_f32_16x16x32_bf16(fq0, gf0, zero, 0, 0, 0);
    f32x4 d1 = __builtin_amdgcn_mfma_f32_16x16x32_bf16(fq1, gf0, zero, 0, 0, 0);
    f32x4 d2 = __builtin_amdgcn_mfma_f32_16x16x32_bf16(fq0, gf1, zero, 0, 0, 0);
    f32x4 d3 = __builtin_amdgcn_mfma_f32_16x16x32_bf16(fq1, gf1, zero, 0, 0, 0);
    bf16x8 ef0, ef1;
    #pragma unroll
    for (int r = 0; r < 4; ++r) {
      ef0[r]     = (__bf16)__builtin_amdgcn_exp2f(d0[r]);
      ef0[4 + r] = (__bf16)__builtin_amdgcn_exp2f(d1[r]);
      ef1[r]     = (__bf16)__builtin_amdgcn_exp2f(d2[r]);
      ef1[4 + r] = (__bf16)__builtin_amdgcn_exp2f(d3[r]);
    }
    acc[0]  = __builtin_amdgcn_mfma_f32_16x16x32_bf16(a0, ef0, acc[0],  0, 0, 0);
    acc2[0] = __builtin_amdgcn_mfma_f32_16x16x32_bf16(a0, ef1, acc2[0], 0, 0, 0);
    acc[1]  = __builtin_amdgcn_mfma_f32_16x16x32_bf16(a1, ef0, acc[1],  0, 0, 0);
    acc2[1] = __builtin_amdgcn_mfma_f32_16x16x32_bf16(a1, ef1, acc2[1], 0, 0, 0);
    acc[2]  = __builtin_amdgcn_mfma_f32_16x16x32_bf16(a2, ef0, acc[2],  0, 0, 0);
    acc2[2] = __builtin_amdgcn_mfma_f32_16x16x32_bf16(a2, ef1, acc2[2], 0, 0, 0);
    acc[3]  = __builtin_amdgcn_mfma_f32_16x16x32_bf16(a3, ef0, acc[3],  0, 0, 0);
    acc2[3] = __builtin_amdgcn_mfma_f32_16x16x32_bf16(a3, ef1, acc2[3], 0, 0, 0);
    acc[4]  = __builtin_amdgcn_mfma_f32_16x16x32_bf16(a4, ef0, acc[4],  0, 0, 0);
    acc2[4] = __builtin_amdgcn_mfma_f32_16x16x32_bf16(a4, ef1, acc2[4], 0, 0, 0);
    acc[5]  = __builtin_amdgcn_mfma_f32_16x16x32_bf16(a5, ef0, acc[5],  0, 0, 0);
    acc2[5] = __builtin_amdgcn_mfma_f32_16x16x32_bf16(a5, ef1, acc2[5], 0, 0, 0);
    acc[6]  = __builtin_amdgcn_mfma_f32_16x16x32_bf16(a6, ef0, acc[6],  0, 0, 0);
    acc2[6] = __builtin_amdgcn_mfma_f32_16x16x32_bf16(a6, ef1, acc2[6], 0, 0, 0);
    acc[7]  = __builtin_amdgcn_mfma_f32_16x16x32_bf16(a7, ef0, acc[7],  0, 0, 0);
    acc2[7] = __builtin_amdgcn_mfma_f32_16x16x32_bf16(a7, ef1, acc2[7], 0, 0, 0);
    if (it < 63) {
      a0 = pa0; a1 = pa1; a2 = pa2; a3 = pa3;
      a4 = pa4; a5 = pa5; a6 = pa6; a7 = pa7;
      fq0 = nf0; fq1 = nf1;
    }
  }

  // epilogue: jh=1 waves dump partials, jh=0 adds + writes out.
  __syncthreads();
  const int region = msub * 4096;                   // 4 regions x 16KB (floats)
  if (jh == 1) {
    #pragma unroll
    for (int ct = 0; ct < 8; ++ct) {
      *(f32x4*)&red[region + ((ct * 2 + 0) * 64 + lane) * 4] = acc[ct];
      *(f32x4*)&red[region + ((ct * 2 + 1) * 64 + lane) * 4] = acc2[ct];
    }
  }
  __syncthreads();
  if (jh == 0) {
    const float gm = gamma[0];
    const float* xb = x + (size_t)b * (256 * 4096);
    float* ob = out + (size_t)b * (256 * 4096);
    #pragma unroll
    for (int ct = 0; ct < 8; ++ct) {
      #pragma unroll
      for (int mt = 0; mt < 2; ++mt) {
        f32x4 o = *(const f32x4*)&red[region + ((ct * 2 + mt) * 64 + lane) * 4];
        o += (mt == 0) ? acc[ct] : acc2[ct];
        #pragma unroll
        for (int r = 0; r < 4; ++r) {
          const int c = ch * 128 + ct * 16 + h * 4 + r;
          const size_t idx = (size_t)c * 4096 + (mbase + mt * 16 + r16);
          ob[idx] = gm * o[r] + xb[idx];
        }
      }
    }
  }
}

extern "C" void kernel_launch(void* const* d_in, const int* in_sizes, int n_in,
                              void* d_out, int out_size, void* d_ws, size_t ws_size,
                              hipStream_t stream) {
  const float* x     = (const float*)d_in[0];
  const float* fw    = (const float*)d_in[1];
  const float* fb    = (const float*)d_in[2];
  const float* gw    = (const float*)d_in[3];
  const float* gb    = (const float*)d_in[4];
  const float* hw    = (const float*)d_in[5];
  const float* hb    = (const float*)d_in[6];
  const float* gamma = (const float*)d_in[7];
  float* out = (float*)d_out;

  char* wsb = (char*)d_ws;
  __bf16* gT  = (__bf16*)(wsb);
  __bf16* fF  = (__bf16*)(wsb + 1048576);
  __bf16* hvF = (__bf16*)(wsb + 2097152);
  float*  Lp  = (float*) (wsb + 10485760);

  k_proj<<<dim3(512), dim3(256), 0, stream>>>(fw, gw, hw, x, fb, gb, hb, gT, fF, hvF);
  k_pass1<<<dim3(1024), dim3(256), 0, stream>>>(gT, fF, Lp);
  k_wdiv<<<dim3(512), dim3(256), 0, stream>>>(hvF, Lp);
  k_pass2<<<dim3(256), dim3(512), 0, stream>>>(gT, fF, hvF, x, gamma, out);
}